// Round 1
// 237.178 us; speedup vs baseline: 1.0025x; 1.0025x over previous
//
#include <hip/hip_runtime.h>

// PCEN: M_t = (1-s) M_{t-1} + s x_t (IIR along T, T=2048 contiguous per row),
// out = (x*(eps+M)^-alpha + bias)^power - bias^power.
//
// v2: barrier-free, LDS-free. One wave per row; each lane owns 8 CONTIGUOUS
// elements per 512-elem chunk (2 float4 loads / 2 float4 stores per lane:
// 32B/lane stride covers every cacheline across adjacent instructions, so
// coalescing survives without the LDS transpose). Per chunk: lane-local scan
// of 8 elems, Kogge-Stone wave scan of affine carries (factor A^8), carry
// chained across chunks through a lane-0 seed. Loads for chunk c+2 are issued
// while chunk c computes; with no s_barrier there is no vmcnt(0) drain, so
// the compiler's counted vmcnt keeps them in flight (depth-2 pipeline).
// Zero LDS + ~50 VGPR -> __launch_bounds__(256,8) = 32 waves/CU.

#define T_LEN 2048
#define CHUNK 512            // elems per chunk; 4 chunks per row
#define PLANE 8              // elems per lane per chunk

__device__ __forceinline__ float fast_exp2(float x) { return __builtin_amdgcn_exp2f(x); }
__device__ __forceinline__ float fast_log2(float x) { return __builtin_amdgcn_logf(x); }

__global__ __launch_bounds__(256, 8) void pcen_kernel(
    const float* __restrict__ x,
    const float* __restrict__ alpha_p,
    const float* __restrict__ power_p,
    const float* __restrict__ bias_p,
    float* __restrict__ out)
{
    const int wave = threadIdx.x >> 6;
    const int lane = threadIdx.x & 63;
    const int row  = (blockIdx.x << 2) | wave;

    const float alpha = alpha_p[0];
    const float power = power_p[0];
    const float bias  = bias_p[0];

    const float A = 0.985f;   // 1 - SMOOTH
    const float S = 0.015f;   // SMOOTH
    float f8 = A * A; f8 *= f8; f8 *= f8;     // A^8 (exact squarings)

    const float* xr  = x   + (size_t)row * T_LEN + PLANE * lane;
    float*       orw = out + (size_t)row * T_LEN + PLANE * lane;

    const float bias_pow = fast_exp2(power * fast_log2(bias));
    const float nalpha   = -alpha;

    float carry = 0.0f;   // absolute M at last element before current chunk

    // ---- prefetch chunks 0 and 1 ----
    float4 a0 = *reinterpret_cast<const float4*>(xr + 0 * CHUNK);
    float4 b0 = *reinterpret_cast<const float4*>(xr + 0 * CHUNK + 4);
    float4 a1 = *reinterpret_cast<const float4*>(xr + 1 * CHUNK);
    float4 b1 = *reinterpret_cast<const float4*>(xr + 1 * CHUNK + 4);
    float4 a2, b2, a3, b3;

#define PROC(cc, va, vb)                                                      \
  {                                                                           \
    float xv[PLANE];                                                          \
    xv[0] = va.x; xv[1] = va.y; xv[2] = va.z; xv[3] = va.w;                   \
    xv[4] = vb.x; xv[5] = vb.y; xv[6] = vb.z; xv[7] = vb.w;                   \
    float mv[PLANE];                                                          \
    float m = 0.0f;                                                           \
    _Pragma("unroll")                                                         \
    for (int j = 0; j < PLANE; ++j) { m = A * m + S * xv[j]; mv[j] = m; }     \
    /* seed lane 0's end-state with the incoming chunk carry, then          */\
    /* Kogge-Stone decay-scan: S_i = m_i + f*S_{i-1}, f = A^8.              */\
    float s = (lane == 0) ? fmaf(f8, carry, m) : m;                           \
    float g = f8;                                                             \
    _Pragma("unroll")                                                         \
    for (int d = 1; d < 64; d <<= 1) {                                        \
      float so = __shfl_up(s, d, 64);                                         \
      if (lane >= d) s = fmaf(g, so, s);                                      \
      g *= g;                                                                 \
    }                                                                         \
    float C = __shfl_up(s, 1, 64);   /* exclusive: abs M before lane's x0 */  \
    if (lane == 0) C = carry;                                                 \
    carry = __shfl(s, 63, 64);       /* abs M at chunk end -> next chunk */   \
    float pa = A * C;                /* A^(j+1) * C, incrementally */         \
    _Pragma("unroll")                                                         \
    for (int j = 0; j < PLANE; ++j) {                                         \
      float M   = mv[j] + pa;                                                 \
      pa *= A;                                                                \
      float den = 1e-9f + M;                                                  \
      float t   = fmaf(xv[j], fast_exp2(nalpha * fast_log2(den)), bias);      \
      xv[j]     = fast_exp2(power * fast_log2(t)) - bias_pow;                 \
    }                                                                         \
    float4 w0, w1;                                                            \
    w0.x = xv[0]; w0.y = xv[1]; w0.z = xv[2]; w0.w = xv[3];                   \
    w1.x = xv[4]; w1.y = xv[5]; w1.z = xv[6]; w1.w = xv[7];                   \
    *reinterpret_cast<float4*>(orw + (cc) * CHUNK)     = w0;                  \
    *reinterpret_cast<float4*>(orw + (cc) * CHUNK + 4) = w1;                  \
  }

    // ---- pipelined chunk loop (fully unrolled, depth-2 prefetch) ----
    a2 = *reinterpret_cast<const float4*>(xr + 2 * CHUNK);
    b2 = *reinterpret_cast<const float4*>(xr + 2 * CHUNK + 4);
    PROC(0, a0, b0);
    a3 = *reinterpret_cast<const float4*>(xr + 3 * CHUNK);
    b3 = *reinterpret_cast<const float4*>(xr + 3 * CHUNK + 4);
    PROC(1, a1, b1);
    PROC(2, a2, b2);
    PROC(3, a3, b3);
#undef PROC
}

extern "C" void kernel_launch(void* const* d_in, const int* in_sizes, int n_in,
                              void* d_out, int out_size, void* d_ws, size_t ws_size,
                              hipStream_t stream) {
    const float* x       = (const float*)d_in[0];
    const float* alpha_p = (const float*)d_in[1];
    const float* power_p = (const float*)d_in[2];
    const float* bias_p  = (const float*)d_in[3];
    float* out           = (float*)d_out;

    const int nrows  = in_sizes[0] / T_LEN;   // 16384, divisible by 4
    const int blocks = nrows / 4;

    pcen_kernel<<<blocks, 256, 0, stream>>>(x, alpha_p, power_p, bias_p, out);
}

// Round 3
// 235.950 us; speedup vs baseline: 1.0077x; 1.0052x over previous
//
#include <hip/hip_runtime.h>

// PCEN: M_t = (1-s) M_{t-1} + s x_t (IIR along T, T=2048 contiguous per row),
// out = (x*(eps+M)^-alpha + bias)^power - bias^power.
//
// v3b: identical to v3 (barrier-free, LDS-free, perfectly coalesced,
// decoupled scans); resubmitted after an infra-side container failure.
// Only change: __launch_bounds__(256,4) (128-VGPR cap) to rule out any
// register-pressure pathology from the tighter (256,6) bound.
//
//  - One wave per row. Lane owns 4 CONTIGUOUS elems per 256-elem chunk ->
//    every global load/store instr is a contiguous 1KB wave access (16
//    cachelines, the optimum; v2's 32B/lane stride touched 32 lines/instr).
//  - All 8 chunk loads issued upfront (8KB/wave in flight).
//  - The 8 chunk scans are CARRY-FREE and independent: Kogge-Stone over
//    segment end-states with factor f=A^4, all 8 chunks interleaved per step
//    so the 48 ds_bpermute latencies overlap (v2 serialized 4 chunks through
//    a lane-0 carry seed -> 4 dependent 8-deep shuffle chains).
//  - Inter-chunk carry is a scalar recurrence R <- s63 + A^256 * R (8 FMAs),
//    applied per-lane via precomputed f^lane = A^(4*lane) (6 select-muls).

#define T_LEN 2048
#define NCH   8            // chunks per row
#define CHUNK 256          // elems per chunk = 64 lanes * 4

__device__ __forceinline__ float fast_exp2(float x) { return __builtin_amdgcn_exp2f(x); }
__device__ __forceinline__ float fast_log2(float x) { return __builtin_amdgcn_logf(x); }
__device__ __forceinline__ float readlane63(float v) {
    return __int_as_float(__builtin_amdgcn_readlane(__float_as_int(v), 63));
}

__global__ __launch_bounds__(256, 4) void pcen_kernel(
    const float* __restrict__ x,
    const float* __restrict__ alpha_p,
    const float* __restrict__ power_p,
    const float* __restrict__ bias_p,
    float* __restrict__ out)
{
    const int wave = threadIdx.x >> 6;
    const int lane = threadIdx.x & 63;
    const int row  = (blockIdx.x << 2) | wave;

    const float alpha = alpha_p[0];
    const float power = power_p[0];
    const float bias  = bias_p[0];

    const float A = 0.985f;   // 1 - SMOOTH
    const float S = 0.015f;   // SMOOTH
    const float A2 = A * A;
    const float f4 = A2 * A2; // A^4: per-segment decay

    const float* xr  = x   + (size_t)row * T_LEN + 4 * lane;
    float*       orw = out + (size_t)row * T_LEN + 4 * lane;

    // ---- issue ALL chunk loads upfront (8 x contiguous 1KB wave-loads) ----
    float4 v[NCH];
#pragma unroll
    for (int c = 0; c < NCH; ++c)
        v[c] = *reinterpret_cast<const float4*>(xr + c * CHUNK);

    // ---- f^lane = A^(4*lane) via 6 select-muls; afterwards t = A^256 ----
    float fl = 1.0f, t = f4;
#pragma unroll
    for (int b = 1; b < 64; b <<= 1) {
        fl = (lane & b) ? fl * t : fl;
        t *= t;
    }
    const float F = t;        // A^256: whole-chunk decay

    // ---- lane-local scans (carry-free): segment end-state per chunk ----
    float s[NCH];
#pragma unroll
    for (int c = 0; c < NCH; ++c) {
        float m = 0.0f;
        m = fmaf(A, m, S * v[c].x);
        m = fmaf(A, m, S * v[c].y);
        m = fmaf(A, m, S * v[c].z);
        m = fmaf(A, m, S * v[c].w);
        s[c] = m;
    }

    // ---- Kogge-Stone inclusive scans, 8 chunks interleaved per step ----
    // combine: s_i = m_i + f * s_{i-1}; multiplier at offset d is f4^d.
    {
        float g = f4;
#pragma unroll
        for (int d = 1; d < 64; d <<= 1) {
#pragma unroll
            for (int c = 0; c < NCH; ++c) {
                const float so = __shfl_up(s[c], d, 64);
                if (lane >= d) s[c] = fmaf(g, so, s[c]);
            }
            g *= g;
        }
    }

    // ---- exclusive prefixes ----
    float e[NCH];
#pragma unroll
    for (int c = 0; c < NCH; ++c) {
        e[c] = __shfl_up(s[c], 1, 64);
        if (lane == 0) e[c] = 0.0f;
    }

    const float bias_pow = fast_exp2(power * fast_log2(bias));
    const float nalpha   = -alpha;

    // ---- apply carries + epilogue, chunk by chunk ----
    float R = 0.0f;           // absolute M at end of previous chunk (uniform)
#pragma unroll
    for (int c = 0; c < NCH; ++c) {
        const float s63 = readlane63(s[c]);
        // abs M just before this lane's first element of chunk c:
        float M = fmaf(fl, R, e[c]);
        R = fmaf(F, R, s63);  // advance uniform chunk carry

        float4 r;
#pragma unroll
        for (int j = 0; j < 4; ++j) {
            const float xj = (j == 0) ? v[c].x : (j == 1) ? v[c].y
                           : (j == 2) ? v[c].z : v[c].w;
            M = fmaf(A, M, S * xj);
            const float den = 1e-9f + M;
            const float tt  = fmaf(xj, fast_exp2(nalpha * fast_log2(den)), bias);
            const float rr  = fast_exp2(power * fast_log2(tt)) - bias_pow;
            if (j == 0) r.x = rr; else if (j == 1) r.y = rr;
            else if (j == 2) r.z = rr; else r.w = rr;
        }
        *reinterpret_cast<float4*>(orw + c * CHUNK) = r;   // contiguous 1KB
    }
}

extern "C" void kernel_launch(void* const* d_in, const int* in_sizes, int n_in,
                              void* d_out, int out_size, void* d_ws, size_t ws_size,
                              hipStream_t stream) {
    const float* x       = (const float*)d_in[0];
    const float* alpha_p = (const float*)d_in[1];
    const float* power_p = (const float*)d_in[2];
    const float* bias_p  = (const float*)d_in[3];
    float* out           = (float*)d_out;

    const int nrows  = in_sizes[0] / T_LEN;   // 16384, divisible by 4
    const int blocks = nrows / 4;

    pcen_kernel<<<blocks, 256, 0, stream>>>(x, alpha_p, power_p, bias_p, out);
}